// Round 8
// baseline (2451.792 us; speedup 1.0000x reference)
//
#include <hip/hip_runtime.h>
#include <stdint.h>

#define BB 128
#define NN 512
#define FF 63
#define HH 128
#define KTOT 320   // 64 + 2*128
#define C5H 640    // 5*H
#define MM 2
#define TPB 640
#define KK4 40     // KTOT/2/4 : dword-quads per column
#define WP_DW_PER_M (KK4 * C5H * 4)
#define WP_DWORDS (MM * WP_DW_PER_M)
#define HOFF ((size_t)1 << 20)

// ---------------- helpers ----------------
__device__ __forceinline__ uint32_t f2bf_rne(float f) {
    uint32_t u = __float_as_uint(f);
    return (u + 0x7fffu + ((u >> 16) & 1u)) >> 16;
}
__device__ __forceinline__ float sigm_f(float x) { return 1.0f / (1.0f + __expf(-x)); }
__device__ __forceinline__ float tanh_f(float x) { return 1.0f - 2.0f / (__expf(2.0f * x) + 1.0f); }

// W repack: dword d (within module) = kk4*2560 + col*4 + p ; holds bf16 rows (2kk, 2kk+1), kk=4*kk4+p.
// Per-lane dwordx4 = one column's kk-quad; wave (64 consecutive cols) reads 1KB contiguous.
__global__ void pack_w_kernel(const float* __restrict__ Wg, uint32_t* __restrict__ Wp) {
    int i = blockIdx.x * blockDim.x + threadIdx.x;
    if (i >= WP_DWORDS) return;
    int m   = i / WP_DW_PER_M;
    int d   = i % WP_DW_PER_M;
    int p   = d & 3;
    int col = (d >> 2) % C5H;
    int kk4 = d / (C5H * 4);
    int kk  = kk4 * 4 + p;
    float w0 = Wg[((size_t)m * KTOT + 2 * kk    ) * C5H + col];
    float w1 = Wg[((size_t)m * KTOT + 2 * kk + 1) * C5H + col];
    Wp[i] = f2bf_rne(w0) | (f2bf_rne(w1) << 16);
}

#define DOT2(acc, w, x) asm("v_dot2_f32_bf16 %0, %1, %2, %0" : "+v"(acc) : "v"(w), "v"(x))

// raw barriers: lgkm-only for LDS phases (keeps prefetch loads in flight);
// vmcnt+lgkm at end-of-step (makes the c-store visible to next step's prefetch).
#define BAR_L()  do { asm volatile("s_waitcnt lgkmcnt(0)" ::: "memory"); \
                      __builtin_amdgcn_s_barrier(); \
                      asm volatile("" ::: "memory"); } while (0)
#define BAR_VL() do { asm volatile("s_waitcnt vmcnt(0) lgkmcnt(0)" ::: "memory"); \
                      __builtin_amdgcn_s_barrier(); \
                      asm volatile("" ::: "memory"); } while (0)

__global__ __launch_bounds__(TPB, 1) void tree_lstm_kernel(
    const float* __restrict__ feat,   // (B,N,F)
    const float* __restrict__ treat,  // (B,)
    const float* __restrict__ bgate,  // (M,5H)
    const float* __restrict__ wout,   // (M,H,1)
    const float* __restrict__ bout,   // (M,1)
    const int*   __restrict__ modidx, // (B,N)
    const int*   __restrict__ lchild, // (N,)
    const int*   __restrict__ rchild, // (N,)
    const uint32_t* __restrict__ Wp,  // packed bf16 pairs, [m][kk4][col][4]
    float* __restrict__ cc,           // ws c history f32 [b][t][j]
    float* __restrict__ out)          // (B,N)
{
    __shared__ __align__(16) ushort   h_lds[NN * HH];   // 128 KB bf16 h history
    __shared__ __align__(16) uint32_t comb_x[32];       // packed bf16 x-part (64 vals)
    __shared__ float gatesf[C5H];
    __shared__ float partial[HH];
    __shared__ float bg_l[MM * C5H];
    __shared__ float wo_l[MM * HH];
    __shared__ float bo_l[MM];
    __shared__ int   mod_l[NN], lc_l[NN], rc_l[NN];

    const int tid = threadIdx.x;
    const int b   = blockIdx.x;
    const float trt = treat[b];
    float* __restrict__ cb = cc + (size_t)b * NN * HH;

    for (int i = tid; i < MM * C5H; i += TPB) bg_l[i] = bgate[i];
    for (int i = tid; i < MM * HH;  i += TPB) wo_l[i] = wout[i];
    if (tid < MM) bo_l[tid] = bout[tid];
    for (int i = tid; i < NN; i += TPB) {
        mod_l[i] = modidx[b * NN + i];
        lc_l[i]  = lchild[i];
        rc_l[i]  = rchild[i];
    }
    // prefetch feats for t=0
    float fx0 = 0.f, fx1 = 0.f;
    if (tid < 32) {
        fx0 = feat[(size_t)b * NN * FF + 2 * tid];
        if (tid < 31) fx1 = feat[(size_t)b * NN * FF + 2 * tid + 1];
    }
    BAR_L();

    for (int t = 0; t < NN; ++t) {
        const int m  = mod_l[t];
        const int lc = lc_l[t];
        const int rc = rc_l[t];

        // ---- Phase A: pack x (from prefetched regs), issue next-step feat +
        //      child-cell prefetches. Loads stay in flight across BAR_L. ----
        if (tid < 32) {
            comb_x[tid] = f2bf_rne(fx0) | (f2bf_rne((tid == 31) ? trt : fx1) << 16);
            if (t + 1 < NN) {
                fx0 = feat[((size_t)b * NN + t + 1) * FF + 2 * tid];
                if (tid < 31) fx1 = feat[((size_t)b * NN + t + 1) * FF + 2 * tid + 1];
            }
        }
        float pcl = 0.f, pcr = 0.f;
        if (tid < HH) {
            if (lc >= 0) pcl = cb[(size_t)lc * HH + tid];   // consumed in Phase C
            if (rc >= 0) pcr = cb[(size_t)rc * HH + tid];
        }
        BAR_L();

        // ---- Phase B: issue the ENTIRE step's W stream first (<=40 vmem ops
        //      in flight per thread), then consume with dot2s. ----
        {
            const uint4* w4 = (const uint4*)Wp + (size_t)m * (KK4 * C5H) + tid;
            uint4 wx[8], wl[16], wr[16];
#pragma unroll
            for (int g = 0; g < 8; ++g) wx[g] = w4[(size_t)g * C5H];
            if (lc >= 0) {
#pragma unroll
                for (int g = 0; g < 16; ++g) wl[g] = w4[(size_t)(8 + g) * C5H];
            }
            if (rc >= 0) {
#pragma unroll
                for (int g = 0; g < 16; ++g) wr[g] = w4[(size_t)(24 + g) * C5H];
            }

            float acc = bg_l[m * C5H + tid];
#pragma unroll
            for (int g = 0; g < 8; ++g) {
                uint4 x = *(const uint4*)(comb_x + 4 * g);
                DOT2(acc, wx[g].x, x.x); DOT2(acc, wx[g].y, x.y);
                DOT2(acc, wx[g].z, x.z); DOT2(acc, wx[g].w, x.w);
            }
            if (lc >= 0) {
                const uint32_t* hl = (const uint32_t*)&h_lds[lc * HH];
#pragma unroll
                for (int g = 0; g < 16; ++g) {
                    uint4 x = *(const uint4*)(hl + 4 * g);
                    DOT2(acc, wl[g].x, x.x); DOT2(acc, wl[g].y, x.y);
                    DOT2(acc, wl[g].z, x.z); DOT2(acc, wl[g].w, x.w);
                }
            }
            if (rc >= 0) {
                const uint32_t* hr = (const uint32_t*)&h_lds[rc * HH];
#pragma unroll
                for (int g = 0; g < 16; ++g) {
                    uint4 x = *(const uint4*)(hr + 4 * g);
                    DOT2(acc, wr[g].x, x.x); DOT2(acc, wr[g].y, x.y);
                    DOT2(acc, wr[g].z, x.z); DOT2(acc, wr[g].w, x.w);
                }
            }
            gatesf[tid] = acc;
        }
        BAR_L();

        // ---- Phase C: activation, state writes, output partials ----
        if (tid < HH) {
            float ig  = gatesf[tid];
            float flg = gatesf[HH + tid];
            float frg = gatesf[2 * HH + tid];
            float og  = gatesf[3 * HH + tid];
            float chg = gatesf[4 * HH + tid];
            float cell = sigm_f(ig) * tanh_f(chg) + sigm_f(flg) * pcl + sigm_f(frg) * pcr;
            float hid  = sigm_f(og) * tanh_f(cell);
            cb[(size_t)t * HH + tid] = cell;                       // f32 (accumulating path)
            h_lds[t * HH + tid] = (ushort)f2bf_rne(hid);           // bf16 h history
            partial[tid] = hid * wo_l[m * HH + tid];
        }
        BAR_VL();   // drain c-store so next step's prefetch can't read stale

        // ---- Phase D: wave 0 reduces output; other waves proceed to next A ----
        if (tid < 64) {
            float s = partial[tid] + partial[tid + 64];
#pragma unroll
            for (int off = 32; off; off >>= 1) s += __shfl_down(s, off, 64);
            if (tid == 0) out[(size_t)b * NN + t] = s + bo_l[m];
        }
    }
}

extern "C" void kernel_launch(void* const* d_in, const int* in_sizes, int n_in,
                              void* d_out, int out_size, void* d_ws, size_t ws_size,
                              hipStream_t stream) {
    const float* feat   = (const float*)d_in[0];
    const float* treat  = (const float*)d_in[1];
    const float* Wg     = (const float*)d_in[2];
    const float* bgate  = (const float*)d_in[3];
    const float* wout   = (const float*)d_in[4];
    const float* bout   = (const float*)d_in[5];
    const int*   modidx = (const int*)d_in[6];
    const int*   lchild = (const int*)d_in[7];
    const int*   rchild = (const int*)d_in[8];

    uint32_t* Wp = (uint32_t*)d_ws;
    float* cc  = (float*)((char*)d_ws + HOFF);
    float* out = (float*)d_out;

    pack_w_kernel<<<(WP_DWORDS + 255) / 256, 256, 0, stream>>>(Wg, Wp);
    tree_lstm_kernel<<<BB, TPB, 0, stream>>>(feat, treat, bgate, wout, bout,
                                             modidx, lchild, rchild, Wp, cc, out);
}

// Round 11
// 1370.600 us; speedup vs baseline: 1.7888x; 1.7888x over previous
//
#include <hip/hip_runtime.h>
#include <stdint.h>

#define BB 128
#define NN 512
#define FF 63
#define HH 128
#define C5H 640    // 5*H
#define MM 2
#define TPB 640
#define KK4 40     // dword-quad groups per column (K=320 -> 160 dwords -> 40 quads)
#define WP_DW_PER_M (KK4 * C5H * 4)
#define WP_DWORDS (MM * WP_DW_PER_M)
#define SCAP 128   // LDS stack capacity (equilibrium depth ~5; huge margin)

// ---------------- helpers (R6-identical) ----------------
__device__ __forceinline__ uint32_t f2bf_rne(float f) {
    uint32_t u = __float_as_uint(f);
    return (u + 0x7fffu + ((u >> 16) & 1u)) >> 16;
}
__device__ __forceinline__ float sigm_f(float x) { return 1.0f / (1.0f + __expf(-x)); }
__device__ __forceinline__ float tanh_f(float x) { return 1.0f - 2.0f / (__expf(2.0f * x) + 1.0f); }

// W repack (R6-identical): dword d = kk4*2560 + col*4 + p ; rows (2kk,2kk+1), kk=4*kk4+p.
__global__ void pack_w_kernel(const float* __restrict__ Wg, uint32_t* __restrict__ Wp) {
    int i = blockIdx.x * blockDim.x + threadIdx.x;
    if (i >= WP_DWORDS) return;
    int m   = i / WP_DW_PER_M;
    int d   = i % WP_DW_PER_M;
    int p   = d & 3;
    int col = (d >> 2) % C5H;
    int kk4 = d / (C5H * 4);
    int kk  = kk4 * 4 + p;
    float w0 = Wg[((size_t)m * 320 + 2 * kk    ) * C5H + col];
    float w1 = Wg[((size_t)m * 320 + 2 * kk + 1) * C5H + col];
    Wp[i] = f2bf_rne(w0) | (f2bf_rne(w1) << 16);
}

#define DOT2(acc, w, x) asm("v_dot2_f32_bf16 %0, %1, %2, %0" : "+v"(acc) : "v"(w), "v"(x))

// lgkm-only barrier
#define BAR_L()  do { asm volatile("s_waitcnt lgkmcnt(0)" ::: "memory"); \
                      __builtin_amdgcn_s_barrier(); \
                      asm volatile("" ::: "memory"); } while (0)

// R6's exact streaming dot
__device__ __forceinline__ float seg_dot(float acc, const uint4* __restrict__ w4,
                                         int g0, int ng, const uint32_t* __restrict__ cf) {
#pragma unroll 4
    for (int g = 0; g < ng; ++g) {
        uint4 w = w4[(size_t)(g0 + g) * C5H];          // coalesced 16B/lane
        uint4 x = *(const uint4*)(cf + 4 * g);         // LDS b128 broadcast
        DOT2(acc, w.x, x.x);
        DOT2(acc, w.y, x.y);
        DOT2(acc, w.z, x.z);
        DOT2(acc, w.w, x.w);
    }
    return acc;
}

__global__ __launch_bounds__(TPB, 1) void tree_lstm_kernel(
    const float* __restrict__ feat,   // (B,N,F)
    const float* __restrict__ treat,  // (B,)
    const float* __restrict__ bgate,  // (M,5H)
    const float* __restrict__ wout,   // (M,H,1)
    const float* __restrict__ bout,   // (M,1)
    const int*   __restrict__ modidx, // (B,N)
    const int*   __restrict__ lchild, // (N,)
    const int*   __restrict__ rchild, // (N,)
    const uint32_t* __restrict__ Wp,  // packed bf16 pairs, [m][kk4][col][4]
    float* __restrict__ out)          // (B,N)
{
    // Stack-resident state (only delta vs R6's node-indexed history/global-c)
    __shared__ __align__(16) ushort h_live[SCAP * HH];  // bf16, 32 KB
    __shared__ float               c_live[SCAP * HH];   // f32,  64 KB
    __shared__ __align__(16) uint32_t comb_x[32];       // packed bf16 x-part
    __shared__ float gatesf[C5H];
    __shared__ float partial[HH];
    __shared__ float bg_l[MM * C5H];
    __shared__ float wo_l[MM * HH];
    __shared__ float bo_l[MM];
    __shared__ int   mod_l[NN], lc_l[NN], rc_l[NN];

    const int tid = threadIdx.x;
    const int b   = blockIdx.x;
    const float trt = treat[b];

    for (int i = tid; i < MM * C5H; i += TPB) bg_l[i] = bgate[i];
    for (int i = tid; i < MM * HH;  i += TPB) wo_l[i] = wout[i];
    if (tid < MM) bo_l[tid] = bout[tid];
    for (int i = tid; i < NN; i += TPB) {
        mod_l[i] = modidx[b * NN + i];
        lc_l[i]  = lchild[i];
        rc_l[i]  = rchild[i];
    }

    // prefetch feats for t=0
    float fx0 = 0.f, fx1 = 0.f;
    if (tid < 32) {
        fx0 = feat[(size_t)b * NN * FF + 2 * tid];
        if (tid < 31) fx1 = feat[(size_t)b * NN * FF + 2 * tid + 1];
    }
    BAR_L();

    int sp = 0;  // roots-stack pointer (uniform across block)
    for (int t = 0; t < NN; ++t) {
        const int m  = mod_l[t];
        const bool hasL = lc_l[t] >= 0, hasR = rc_l[t] >= 0;
        const int rh_slot = sp - 1;                    // right child = top
        const int lh_slot = hasR ? sp - 2 : sp - 1;    // left = next (or top)
        const int new_slot = hasL ? lh_slot : sp;      // node t's slot

        // ---- Phase A: pack x from prefetched regs; issue next feat loads ----
        if (tid < 32) {
            comb_x[tid] = f2bf_rne(fx0) | (f2bf_rne((tid == 31) ? trt : fx1) << 16);
            if (t + 1 < NN) {
                fx0 = feat[((size_t)b * NN + t + 1) * FF + 2 * tid];
                if (tid < 31) fx1 = feat[((size_t)b * NN + t + 1) * FF + 2 * tid + 1];
            }
        }
        BAR_L();

        // ---- Phase B: R6's exact dot order: x, then L, then R (streamed) ----
        {
            float acc = bg_l[m * C5H + tid];
            const uint4* w4 = (const uint4*)Wp + (size_t)m * (KK4 * C5H) + tid;
            acc = seg_dot(acc, w4, 0, 8, comb_x);
            if (hasL) acc = seg_dot(acc, w4,  8, 16, (const uint32_t*)&h_live[lh_slot * HH]);
            if (hasR) acc = seg_dot(acc, w4, 24, 16, (const uint32_t*)&h_live[rh_slot * HH]);
            gatesf[tid] = acc;
        }
        BAR_L();

        // ---- Phase C: activation + stack update (all state in LDS) ----
        if (tid < HH) {
            float ig  = gatesf[tid];
            float flg = gatesf[HH + tid];
            float frg = gatesf[2 * HH + tid];
            float og  = gatesf[3 * HH + tid];
            float chg = gatesf[4 * HH + tid];
            float pcl = hasL ? c_live[lh_slot * HH + tid] : 0.0f;
            float pcr = hasR ? c_live[rh_slot * HH + tid] : 0.0f;
            float cell = sigm_f(ig) * tanh_f(chg) + sigm_f(flg) * pcl + sigm_f(frg) * pcr;
            float hid  = sigm_f(og) * tanh_f(cell);
            c_live[new_slot * HH + tid] = cell;
            h_live[new_slot * HH + tid] = (ushort)f2bf_rne(hid);
            partial[tid] = hid * wo_l[m * HH + tid];
        }
        BAR_L();

        // ---- Phase D: wave 0 reduces output (others roll into next A) ----
        if (tid < 64) {
            float s = partial[tid] + partial[tid + 64];
#pragma unroll
            for (int off = 32; off; off >>= 1) s += __shfl_down(s, off, 64);
            if (tid == 0) out[(size_t)b * NN + t] = s + bo_l[m];
        }

        sp = hasR ? sp - 1 : (hasL ? sp : sp + 1);
    }
}

extern "C" void kernel_launch(void* const* d_in, const int* in_sizes, int n_in,
                              void* d_out, int out_size, void* d_ws, size_t ws_size,
                              hipStream_t stream) {
    const float* feat   = (const float*)d_in[0];
    const float* treat  = (const float*)d_in[1];
    const float* Wg     = (const float*)d_in[2];
    const float* bgate  = (const float*)d_in[3];
    const float* wout   = (const float*)d_in[4];
    const float* bout   = (const float*)d_in[5];
    const int*   modidx = (const int*)d_in[6];
    const int*   lchild = (const int*)d_in[7];
    const int*   rchild = (const int*)d_in[8];

    uint32_t* Wp = (uint32_t*)d_ws;
    float* out = (float*)d_out;

    pack_w_kernel<<<(WP_DWORDS + 255) / 256, 256, 0, stream>>>(Wg, Wp);
    tree_lstm_kernel<<<BB, TPB, 0, stream>>>(feat, treat, bgate, wout, bout,
                                             modidx, lchild, rchild, Wp, out);
}